// Round 1
// baseline (4625.217 us; speedup 1.0000x reference)
//
#include <hip/hip_runtime.h>
#include <hip/hip_bf16.h>

// VQ argmin: N tokens x K codes, D-dim, fp32.
// out[0 : N*D)        = quantized (== inputs, since q + (x - q) == x to ref tolerance)
// out[N*D : N*D + N)  = argmin indices, written as float32
//
// ws layout: c2 [0, K) floats, x2 [K, K+N) floats  (needs 160 KiB)

constexpr int NTOK = 32768;
constexpr int DIM  = 512;
constexpr int KC   = 8192;

constexpr int BM = 128, BN = 128, BK = 32;   // block tile; 8x8 per-thread regs
constexpr int NTHREADS = 256;

// ---------------- copy: quantized = inputs ----------------
__global__ void vq_copy(const float* __restrict__ in, float* __restrict__ out, int n4) {
  int i = blockIdx.x * blockDim.x + threadIdx.x;
  int st = gridDim.x * blockDim.x;
  const float4* s = (const float4*)in;
  float4* d = (float4*)out;
  for (; i < n4; i += st) d[i] = s[i];
}

// ---------------- row sum-of-squares (one wave per row of 512) ----------------
__global__ void vq_rowsq(const float* __restrict__ m, float* __restrict__ o, int rows) {
  int w = (blockIdx.x * blockDim.x + threadIdx.x) >> 6;
  int lane = threadIdx.x & 63;
  if (w >= rows) return;
  const float4* r = (const float4*)(m + (size_t)w * DIM);
  float4 a = r[lane];
  float4 b = r[lane + 64];
  float s = a.x*a.x + a.y*a.y + a.z*a.z + a.w*a.w
          + b.x*b.x + b.y*b.y + b.z*b.z + b.w*b.w;
  #pragma unroll
  for (int off = 32; off; off >>= 1) s += __shfl_down(s, off, 64);
  if (lane == 0) o[w] = s;
}

// ---------------- staging: [rows=128][BK=32] f32 tile via global_load_lds ----
// LDS layout is linear [row][8 units of 16B]; bank-swizzle is achieved by
// pre-swizzling the GLOBAL source (rule #21): unit' = unit ^ ((row>>3)&7).
// Reads then apply the same XOR -> <=2-way conflicts (free).
__device__ __forceinline__ void stage_tile(const float* __restrict__ src, int srow,
                                           int k0, float* lbuf, int tid) {
  const int wave = tid >> 6, lane = tid & 63;
  #pragma unroll
  for (int i = 0; i < 4; ++i) {
    const int u   = i * 256 + wave * 64 + lane;   // 16B unit index, 1024 total
    const int row = u >> 3;
    const int k4  = (u & 7) ^ ((row >> 3) & 7);   // pre-swizzled source quad
    const float* g = src + (size_t)(srow + row) * DIM + k0 + (k4 << 2);
    float* l = lbuf + ((i * 256 + wave * 64) << 2);  // wave-uniform LDS base
    __builtin_amdgcn_global_load_lds(
        (const __attribute__((address_space(1))) void*)g,
        (__attribute__((address_space(3))) void*)l, 16, 0, 0);
  }
}

// ---------------- fused distance-argmin ----------------
// Block: BM=128 rows, loops over all K codes in BN=128 col tiles.
// Thread (tr=tid/16, tc=tid%16): rows tr*8+rr, cols tc*8+cc -> 8x8 acc.
// d2 = fl( fl(x2 + c2) - 2*dot )  matches the reference rounding structure
// (2*dot is exact, single rounding on the subtract via fma(-2, dot, s)).
__launch_bounds__(NTHREADS, 1)
__global__ void vq_argmin(const float* __restrict__ X, const float* __restrict__ Cb,
                          const float* __restrict__ c2, const float* __restrict__ x2,
                          float* __restrict__ idx_out) {
  __shared__ __align__(16) float xs[2][BM * BK];   // 16 KiB each
  __shared__ __align__(16) float cs[2][BN * BK];   // total 64 KiB
  const int tid = threadIdx.x;
  const int tr = tid >> 4, tc = tid & 15;
  const int row0 = blockIdx.x * BM;

  float bestd[8];
  int   besti[8];
  #pragma unroll
  for (int rr = 0; rr < 8; ++rr) { bestd[rr] = 3.4e38f; besti[rr] = 0; }

  float x2r[8];
  #pragma unroll
  for (int rr = 0; rr < 8; ++rr) x2r[rr] = x2[row0 + tr * 8 + rr];

  for (int ct = 0; ct < KC / BN; ++ct) {
    float acc[8][8];
    #pragma unroll
    for (int rr = 0; rr < 8; ++rr)
      #pragma unroll
      for (int cc = 0; cc < 8; ++cc) acc[rr][cc] = 0.f;

    stage_tile(X,  row0,    0, &xs[0][0], tid);
    stage_tile(Cb, ct * BN, 0, &cs[0][0], tid);
    __syncthreads();

    for (int kc = 0; kc < DIM / BK; ++kc) {
      const int cur = kc & 1;
      if (kc + 1 < DIM / BK) {   // prefetch next chunk; overlaps with compute below
        stage_tile(X,  row0,    (kc + 1) * BK, &xs[cur ^ 1][0], tid);
        stage_tile(Cb, ct * BN, (kc + 1) * BK, &cs[cur ^ 1][0], tid);
      }
      #pragma unroll
      for (int q = 0; q < BK / 4; ++q) {
        float4 xv[8], cv[8];
        #pragma unroll
        for (int rr = 0; rr < 8; ++rr) {
          const int r = tr * 8 + rr;
          xv[rr] = *(const float4*)&xs[cur][r * BK + ((q ^ ((r >> 3) & 7)) << 2)];
        }
        #pragma unroll
        for (int cc = 0; cc < 8; ++cc) {
          const int cl = tc * 8 + cc;
          cv[cc] = *(const float4*)&cs[cur][cl * BK + ((q ^ ((cl >> 3) & 7)) << 2)];
        }
        #pragma unroll
        for (int rr = 0; rr < 8; ++rr)
          #pragma unroll
          for (int cc = 0; cc < 8; ++cc) {
            acc[rr][cc] = fmaf(xv[rr].x, cv[cc].x, acc[rr][cc]);
            acc[rr][cc] = fmaf(xv[rr].y, cv[cc].y, acc[rr][cc]);
            acc[rr][cc] = fmaf(xv[rr].z, cv[cc].z, acc[rr][cc]);
            acc[rr][cc] = fmaf(xv[rr].w, cv[cc].w, acc[rr][cc]);
          }
      }
      __syncthreads();
    }

    // epilogue for this col-tile: d2 + running argmin (strict < => first-min)
    float c2v[8];
    #pragma unroll
    for (int cc = 0; cc < 8; ++cc) c2v[cc] = c2[ct * BN + tc * 8 + cc];
    #pragma unroll
    for (int rr = 0; rr < 8; ++rr) {
      #pragma unroll
      for (int cc = 0; cc < 8; ++cc) {
        const float d = fmaf(-2.0f, acc[rr][cc], x2r[rr] + c2v[cc]);
        const int ci = ct * BN + tc * 8 + cc;
        if (d < bestd[rr]) { bestd[rr] = d; besti[rr] = ci; }
      }
    }
  }

  // cross-thread reduce: the 16 lanes sharing a row group are contiguous in-wave
  #pragma unroll
  for (int rr = 0; rr < 8; ++rr) {
    float d = bestd[rr];
    int ix = besti[rr];
    #pragma unroll
    for (int off = 1; off < 16; off <<= 1) {
      const float od = __shfl_xor(d, off, 64);
      const int   oi = __shfl_xor(ix, off, 64);
      if (od < d || (od == d && oi < ix)) { d = od; ix = oi; }  // tie -> lower idx
    }
    if (tc == 0) idx_out[row0 + tr * 8 + rr] = (float)ix;
  }
}

extern "C" void kernel_launch(void* const* d_in, const int* in_sizes, int n_in,
                              void* d_out, int out_size, void* d_ws, size_t ws_size,
                              hipStream_t stream) {
  const float* X  = (const float*)d_in[0];   // [N, D] fp32
  const float* Cb = (const float*)d_in[1];   // [K, D] fp32
  float* out = (float*)d_out;
  float* c2 = (float*)d_ws;                  // [K]
  float* x2 = c2 + KC;                       // [N]

  vq_copy<<<2048, NTHREADS, 0, stream>>>(X, out, NTOK * DIM / 4);
  vq_rowsq<<<KC / 4, NTHREADS, 0, stream>>>(Cb, c2, KC);
  vq_rowsq<<<NTOK / 4, NTHREADS, 0, stream>>>(X, x2, NTOK);
  vq_argmin<<<NTOK / BM, NTHREADS, 0, stream>>>(X, Cb, c2, x2,
                                                out + (size_t)NTOK * DIM);
}

// Round 2
// 775.940 us; speedup vs baseline: 5.9608x; 5.9608x over previous
//
#include <hip/hip_runtime.h>
#include <hip/hip_bf16.h>

// VQ argmin via bf16 MFMA + exact fp64 refine.
// out[0:N*D) = inputs (identity); out[N*D : N*D+N) = argmin indices as f32.
// Scratch carved from d_out[0:N*D):
//   Xb  bf16[N][D]   @ float ofs 0         (32 MiB)
//   Cbb bf16[K][D]   @ float ofs 8388608   ( 8 MiB)
//   cand int[N][64]  @ float ofs 12582912  ( 8 MiB)
//   c2  f32[K]       @ float ofs 14680064  (32 KiB)

constexpr int NTOK = 32768, DIM = 512, KCODES = 8192;
constexpr int BM = 128, BN = 128;
constexpr float MARGIN = 3.0f;

using bfrag = __attribute__((ext_vector_type(8))) short;   // 8 bf16 (4 VGPR)
using ffrag = __attribute__((ext_vector_type(4))) float;   // 4 f32 acc
using u16x8 = __attribute__((ext_vector_type(8))) unsigned short;

#define GLD_LDS16(g, l)                                                        \
  __builtin_amdgcn_global_load_lds(                                            \
      (const __attribute__((address_space(1))) void*)(g),                      \
      (__attribute__((address_space(3))) void*)(l), 16, 0, 0)

__device__ __forceinline__ unsigned short f2bf(float x) {  // RNE
  unsigned u = __float_as_uint(x);
  return (unsigned short)((u + 0x7fffu + ((u >> 16) & 1u)) >> 16);
}

// ---- convert fp32 rows -> bf16, optional sum-of-squares (one wave per row) --
__global__ void vq_prep(const float* __restrict__ src, unsigned short* __restrict__ dst,
                        float* __restrict__ sq, int rows) {
  int w = (blockIdx.x * blockDim.x + threadIdx.x) >> 6;
  int lane = threadIdx.x & 63;
  if (w >= rows) return;
  const float4* r4 = (const float4*)(src + (size_t)w * DIM);
  float4 a = r4[lane * 2], b = r4[lane * 2 + 1];
  u16x8 o;
  o[0]=f2bf(a.x); o[1]=f2bf(a.y); o[2]=f2bf(a.z); o[3]=f2bf(a.w);
  o[4]=f2bf(b.x); o[5]=f2bf(b.y); o[6]=f2bf(b.z); o[7]=f2bf(b.w);
  *((u16x8*)(dst + (size_t)w * DIM) + lane) = o;
  if (sq != nullptr) {
    float s = a.x*a.x + a.y*a.y + a.z*a.z + a.w*a.w
            + b.x*b.x + b.y*b.y + b.z*b.z + b.w*b.w;
    #pragma unroll
    for (int off = 32; off; off >>= 1) s += __shfl_down(s, off, 64);
    if (lane == 0) sq[w] = s;
  }
}

// ---- fused bf16 MFMA distance + approx best-2 + candidate emission ---------
__launch_bounds__(256, 1)
__global__ void vq_main(const unsigned short* __restrict__ Xb,
                        const unsigned short* __restrict__ Cbb,
                        const float* __restrict__ c2, int* __restrict__ cand) {
  __shared__ __align__(16) unsigned short As[BM][DIM];    // 128 KiB, X resident
  __shared__ __align__(16) unsigned short Bs[2][BN][32];  // 16 KiB dbuf
  __shared__ unsigned dstar[2][BM];                       // cross-wave row mins
  const int tid = threadIdx.x, lane = tid & 63;
  const int wid = tid >> 6, wr = wid >> 1, wc = wid & 1;
  const int row0 = blockIdx.x * BM;
  const int l15 = lane & 15, l4 = lane >> 4;

  // stage X tile once (pre-swizzled source: unit' = unit ^ (row&7))
  #pragma unroll
  for (int it = 0; it < 32; ++it) {
    int u = it * 256 + tid, r = u >> 6, m = u & 63;
    GLD_LDS16(Xb + (size_t)(row0 + r) * DIM + ((m ^ (r & 7)) << 3),
              &As[0][0] + u * 8);
  }
  // stage first B tile (t=0) into buf 0
  #pragma unroll
  for (int it = 0; it < 2; ++it) {
    int u = it * 256 + tid, r = u >> 2, m = u & 3;
    GLD_LDS16(Cbb + (size_t)r * DIM + ((m ^ ((r >> 1) & 3)) << 3),
              &Bs[0][0][0] + u * 8);
  }
  __syncthreads();

  unsigned b0[4][4], b1[4][4];
  #pragma unroll
  for (int rf = 0; rf < 4; ++rf)
    #pragma unroll
    for (int rg = 0; rg < 4; ++rg) { b0[rf][rg] = 0xFFFFFFFFu; b1[rf][rg] = 0xFFFFFFFFu; }

  ffrag acc[4][4];
  int buf = 0;
  for (int t = 0; t < 64 * 16; ++t) {
    const int ct = t >> 4, kc = t & 15;
    if (t + 1 < 64 * 16) {               // prefetch next B tile into buf^1
      const int ctn = (t + 1) >> 4, kcn = (t + 1) & 15;
      #pragma unroll
      for (int it = 0; it < 2; ++it) {
        int u = it * 256 + tid, r = u >> 2, m = u & 3;
        GLD_LDS16(Cbb + (size_t)(ctn * BN + r) * DIM + kcn * 32 +
                      ((m ^ ((r >> 1) & 3)) << 3),
                  &Bs[buf ^ 1][0][0] + u * 8);
      }
    }
    if (kc == 0) {
      #pragma unroll
      for (int rf = 0; rf < 4; ++rf)
        #pragma unroll
        for (int cf = 0; cf < 4; ++cf) {
          ffrag z = {0.f, 0.f, 0.f, 0.f};
          acc[rf][cf] = z;
        }
    }
    bfrag a[4], b[4];
    #pragma unroll
    for (int rf = 0; rf < 4; ++rf) {
      int r = wr * 64 + rf * 16 + l15, j = kc * 4 + l4;
      a[rf] = *(const bfrag*)&As[r][(j ^ (r & 7)) << 3];
    }
    #pragma unroll
    for (int cf = 0; cf < 4; ++cf) {
      int r = wc * 64 + cf * 16 + l15;
      b[cf] = *(const bfrag*)&Bs[buf][r][(l4 ^ ((r >> 1) & 3)) << 3];
    }
    #pragma unroll
    for (int rf = 0; rf < 4; ++rf)
      #pragma unroll
      for (int cf = 0; cf < 4; ++cf)
        acc[rf][cf] = __builtin_amdgcn_mfma_f32_16x16x32_bf16(a[rf], b[cf], acc[rf][cf], 0, 0, 0);
    __syncthreads();
    buf ^= 1;

    if (kc == 15) {  // per-col-tile epilogue: packed-key best-2 update
      float c2p[4];
      #pragma unroll
      for (int cf = 0; cf < 4; ++cf)
        c2p[cf] = c2[ct * BN + wc * 64 + cf * 16 + l15] + 2048.0f;  // keep key>0
      #pragma unroll
      for (int rf = 0; rf < 4; ++rf)
        #pragma unroll
        for (int rg = 0; rg < 4; ++rg) {
          unsigned kk[4];
          #pragma unroll
          for (int cf = 0; cf < 4; ++cf) {
            float d = fmaf(-2.0f, acc[rf][cf][rg], c2p[cf]);
            kk[cf] = (__float_as_uint(d) & 0xFFFFFF00u) | (unsigned)((ct << 2) | cf);
          }
          unsigned kmin = min(min(kk[0], kk[1]), min(kk[2], kk[3]));
          unsigned mx = max(b0[rf][rg], kmin);
          b0[rf][rg] = min(b0[rf][rg], kmin);
          b1[rf][rg] = min(b1[rf][rg], mx);
        }
    }
  }

  // per-row group min (16 lanes sharing l4 hold a row), cross-wave via LDS
  unsigned gmin[4][4];
  #pragma unroll
  for (int rf = 0; rf < 4; ++rf)
    #pragma unroll
    for (int rg = 0; rg < 4; ++rg) {
      unsigned g = b0[rf][rg];
      #pragma unroll
      for (int m = 1; m < 16; m <<= 1)
        g = min(g, (unsigned)__shfl_xor((int)g, m, 64));
      gmin[rf][rg] = g;
      if (l15 == 0) dstar[wc][wr * 64 + rf * 16 + l4 * 4 + rg] = g;
    }
  __syncthreads();
  #pragma unroll
  for (int rf = 0; rf < 4; ++rf)
    #pragma unroll
    for (int rg = 0; rg < 4; ++rg) {
      int rl = wr * 64 + rf * 16 + l4 * 4 + rg;
      unsigned gg = min(gmin[rf][rg], dstar[wc ^ 1][rl]);
      float ds = __uint_as_float(gg & 0xFFFFFF00u);
      unsigned thr = __float_as_uint(ds + MARGIN);
      int base = (row0 + rl) * 64 + wc * 32 + l15 * 2;
      unsigned k0 = b0[rf][rg], k1 = b1[rf][rg];
      int c0 = (int)(((k0 >> 2) & 63u) * 128u) + wc * 64 + (int)(k0 & 3u) * 16 + l15;
      int c1 = (int)(((k1 >> 2) & 63u) * 128u) + wc * 64 + (int)(k1 & 3u) * 16 + l15;
      cand[base + 0] = (k0 <= thr) ? c0 : -1;
      cand[base + 1] = (k1 <= thr) ? c1 : -1;
    }
}

// ---- exact fp64 refine over candidate set (one wave per row) ---------------
__global__ void vq_refine(const float* __restrict__ X, const float* __restrict__ Cb,
                          const int* __restrict__ cand, float* __restrict__ idx_out) {
  int row = (blockIdx.x * blockDim.x + threadIdx.x) >> 6;
  int lane = threadIdx.x & 63;
  if (row >= NTOK) return;
  int cv = cand[row * 64 + lane];
  unsigned long long mask = __ballot(cv >= 0);
  if (__popcll(mask) == 1) {
    int src = __ffsll(mask) - 1;
    int idx = __shfl(cv, src, 64);
    if (lane == 0) idx_out[row] = (float)idx;
    return;
  }
  const float4* x4 = (const float4*)(X + (size_t)row * DIM);
  float4 xa = x4[lane * 2], xb = x4[lane * 2 + 1];
  double bestd = 1e300; int besti = 0;
  unsigned long long mm = mask;
  while (mm) {
    int src = __ffsll(mm) - 1; mm &= mm - 1;
    int idx = __shfl(cv, src, 64);
    const float4* c4 = (const float4*)(Cb + (size_t)idx * DIM);
    float4 ca = c4[lane * 2], cb = c4[lane * 2 + 1];
    double dt = (double)xa.x*ca.x + (double)xa.y*ca.y + (double)xa.z*ca.z + (double)xa.w*ca.w
              + (double)xb.x*cb.x + (double)xb.y*cb.y + (double)xb.z*cb.z + (double)xb.w*cb.w;
    double cc = (double)ca.x*ca.x + (double)ca.y*ca.y + (double)ca.z*ca.z + (double)ca.w*ca.w
              + (double)cb.x*cb.x + (double)cb.y*cb.y + (double)cb.z*cb.z + (double)cb.w*cb.w;
    double s = cc - 2.0 * dt;               // x2 omitted: per-row constant
    #pragma unroll
    for (int off = 32; off; off >>= 1) s += __shfl_down(s, off, 64);
    if (lane == 0 && (s < bestd || (s == bestd && idx < besti))) { bestd = s; besti = idx; }
  }
  if (lane == 0) idx_out[row] = (float)besti;
}

// ---- final: quantized = inputs (runs LAST; overwrites scratch) -------------
__global__ void vq_copy(const float* __restrict__ in, float* __restrict__ out, int n4) {
  int i = blockIdx.x * blockDim.x + threadIdx.x;
  int st = gridDim.x * blockDim.x;
  const float4* s = (const float4*)in;
  float4* d = (float4*)out;
  for (; i < n4; i += st) d[i] = s[i];
}

extern "C" void kernel_launch(void* const* d_in, const int* in_sizes, int n_in,
                              void* d_out, int out_size, void* d_ws, size_t ws_size,
                              hipStream_t stream) {
  const float* X  = (const float*)d_in[0];
  const float* Cb = (const float*)d_in[1];
  float* out = (float*)d_out;

  unsigned short* Xb  = (unsigned short*)out;                 // [N][D] bf16
  unsigned short* Cbb = (unsigned short*)(out + 8388608);     // [K][D] bf16
  int*            cand = (int*)(out + 12582912);              // [N][64]
  float*          c2   = out + 14680064;                      // [K]
  float*          idx_out = out + (size_t)NTOK * DIM;

  vq_prep<<<KCODES / 4, 256, 0, stream>>>(Cb, Cbb, c2, KCODES);
  vq_prep<<<NTOK / 4, 256, 0, stream>>>(X, Xb, nullptr, NTOK);
  vq_main<<<NTOK / BM, 256, 0, stream>>>(Xb, Cbb, c2, cand);
  vq_refine<<<NTOK / 4, 256, 0, stream>>>(X, Cb, cand, idx_out);
  vq_copy<<<2048, 256, 0, stream>>>(X, out, NTOK * DIM / 4);
}

// Round 3
// 509.578 us; speedup vs baseline: 9.0766x; 1.5227x over previous
//
#include <hip/hip_runtime.h>
#include <hip/hip_bf16.h>

// VQ argmin via bf16 MFMA + exact fp64 refine. Round 3: software-pipelined
// vq_main (raw s_barrier + counted vmcnt, B ring-3, reg-dbuf fragments).
// out[0:N*D) = inputs; out[N*D : N*D+N) = argmin indices as f32.
// Scratch carved from d_out[0:N*D):
//   Xb  bf16[N][D]   @ float ofs 0         (32 MiB)
//   Cbb bf16[K][D]   @ float ofs 8388608   ( 8 MiB)
//   cand int[N][64]  @ float ofs 12582912  ( 8 MiB)
//   c2  f32[K]       @ float ofs 14680064  (32 KiB)

constexpr int NTOK = 32768, DIM = 512, KCODES = 8192;
constexpr int BM = 128, BN = 128;
constexpr int NCT = KCODES / BN;   // 64 col-tiles
constexpr int TT  = NCT * 16;      // 1024 k-tiles (BK=32)
constexpr float MARGIN = 3.0f;

using bfrag = __attribute__((ext_vector_type(8))) short;   // 8 bf16 (4 VGPR)
using ffrag = __attribute__((ext_vector_type(4))) float;   // 4 f32 acc
using u16x8 = __attribute__((ext_vector_type(8))) unsigned short;

#define GLD_LDS16(g, l)                                                        \
  __builtin_amdgcn_global_load_lds(                                            \
      (const __attribute__((address_space(1))) void*)(g),                      \
      (__attribute__((address_space(3))) void*)(l), 16, 0, 0)

__device__ __forceinline__ unsigned short f2bf(float x) {  // RNE
  unsigned u = __float_as_uint(x);
  return (unsigned short)((u + 0x7fffu + ((u >> 16) & 1u)) >> 16);
}

// ---- convert fp32 rows -> bf16, optional sum-of-squares (one wave per row) --
__global__ void vq_prep(const float* __restrict__ src, unsigned short* __restrict__ dst,
                        float* __restrict__ sq, int rows) {
  int w = (blockIdx.x * blockDim.x + threadIdx.x) >> 6;
  int lane = threadIdx.x & 63;
  if (w >= rows) return;
  const float4* r4 = (const float4*)(src + (size_t)w * DIM);
  float4 a = r4[lane * 2], b = r4[lane * 2 + 1];
  u16x8 o;
  o[0]=f2bf(a.x); o[1]=f2bf(a.y); o[2]=f2bf(a.z); o[3]=f2bf(a.w);
  o[4]=f2bf(b.x); o[5]=f2bf(b.y); o[6]=f2bf(b.z); o[7]=f2bf(b.w);
  *((u16x8*)(dst + (size_t)w * DIM) + lane) = o;
  if (sq != nullptr) {
    float s = a.x*a.x + a.y*a.y + a.z*a.z + a.w*a.w
            + b.x*b.x + b.y*b.y + b.z*b.z + b.w*b.w;
    #pragma unroll
    for (int off = 32; off; off >>= 1) s += __shfl_down(s, off, 64);
    if (lane == 0) sq[w] = s;
  }
}

// ---- fused bf16 MFMA distance + approx best-2 + candidate emission ---------
__launch_bounds__(256, 1)
__global__ void vq_main(const unsigned short* __restrict__ Xb,
                        const unsigned short* __restrict__ Cbb,
                        const float* __restrict__ c2g, int* __restrict__ cand) {
  __shared__ __align__(16) unsigned short As[BM][DIM];      // 128 KiB, X resident
  __shared__ __align__(16) unsigned short Bs[3][BN][32];    // 24 KiB ring-3
  __shared__ __align__(16) float c2s[2][BN];                // 1 KiB ring-2
  __shared__ unsigned dstar[2][BM];                         // 1 KiB
  const int tid = threadIdx.x, lane = tid & 63;
  const int wid = tid >> 6, wr = wid >> 1, wc = wid & 1;
  const int row0 = blockIdx.x * BM;
  const int l15 = lane & 15, l4 = lane >> 4;

  // ---------- prologue staging ----------
  #pragma unroll
  for (int it = 0; it < 32; ++it) {   // X tile, pre-swizzled source
    int u = it * 256 + tid, r = u >> 6, m = u & 63;
    GLD_LDS16(Xb + (size_t)(row0 + r) * DIM + ((m ^ (r & 7)) << 3),
              &As[0][0] + u * 8);
  }
  #pragma unroll
  for (int t0 = 0; t0 < 3; ++t0) {    // B tiles 0..2 into slots 0..2
    #pragma unroll
    for (int i2 = 0; i2 < 2; ++i2) {
      int u = i2 * 256 + tid, r = u >> 2, m = u & 3;
      GLD_LDS16(Cbb + (size_t)r * DIM + t0 * 32 + ((m ^ ((r >> 1) & 3)) << 3),
                &Bs[t0][0][0] + u * 8);
    }
  }
  if (lane < 32) GLD_LDS16(c2g + lane * 4, &c2s[0][0] + lane * 4);
  // per-wave in flight: As(32) B0(2) B1(2) B2(2) c2(1); keep 5 -> As+B0 landed
  asm volatile("s_waitcnt vmcnt(5)" ::: "memory");
  __builtin_amdgcn_s_barrier();

  bfrag aPerm[4][4], aF[2][4], bF[2][4];
  #pragma unroll
  for (int rf = 0; rf < 4; ++rf) {    // tile-0 a-frags (kc=0 -> aPerm[0])
    int r = wr * 64 + rf * 16 + l15, j = l4;
    aPerm[0][rf] = *(const bfrag*)&As[r][(j ^ (r & 7)) << 3];
  }
  #pragma unroll
  for (int cf = 0; cf < 4; ++cf) {    // tile-0 b-frags
    int r = wc * 64 + cf * 16 + l15;
    bF[0][cf] = *(const bfrag*)&Bs[0][r][(l4 ^ ((r >> 1) & 3)) << 3];
  }

  unsigned b0k[4][4], b1k[4][4];
  #pragma unroll
  for (int rf = 0; rf < 4; ++rf)
    #pragma unroll
    for (int rg = 0; rg < 4; ++rg) { b0k[rf][rg] = 0xFFFFFFFFu; b1k[rf][rg] = 0xFFFFFFFFu; }
  ffrag acc[4][4];

  for (int ct = 0; ct < NCT; ++ct) {
    #pragma unroll
    for (int kc = 0; kc < 16; ++kc) {
      const int t = ct * 16 + kc;
      // drain own ds_reads (they completed under the previous MFMAs), then sync
      asm volatile("s_waitcnt lgkmcnt(0)" ::: "memory");
      __builtin_amdgcn_s_barrier();
      // counted vmcnt: tile t+1 (staged 2 iters ago) now proven landed;
      // allow stage(t+2) [2 loads] (+ c2 issued last iter when kc==1) in flight
      if (kc == 1) asm volatile("s_waitcnt vmcnt(3)" ::: "memory");
      else         asm volatile("s_waitcnt vmcnt(2)" ::: "memory");

      // stage B tile t+3 into slot (t+3)%3 (overwrites tile t: its frags were
      // read at iter t-1 and lgkm-drained before this barrier on every wave)
      const int tt = t + 3;
      if (tt < TT) {
        const int ctn = tt >> 4, kn = tt & 15, sl = tt % 3;
        #pragma unroll
        for (int i2 = 0; i2 < 2; ++i2) {
          int u = i2 * 256 + tid, r = u >> 2, m = u & 3;
          GLD_LDS16(Cbb + (size_t)(ctn * BN + r) * DIM + kn * 32 +
                        ((m ^ ((r >> 1) & 3)) << 3),
                    &Bs[sl][0][0] + u * 8);
        }
      }
      if (kc == 0 && lane < 32)   // c2 for this ct (used at kc==15; ring-2)
        GLD_LDS16(c2g + ct * BN + lane * 4, &c2s[ct & 1][0] + lane * 4);

      // prefetch tile t+1 fragments (overlap with this iter's MFMAs)
      if (t + 1 < TT) {
        const int kcn = (kc + 1) & 15;   // static after unroll
        const int pn  = (kc + 1) & 1;    // static
        const int sln = (t + 1) % 3;     // runtime (address only)
        #pragma unroll
        for (int cf = 0; cf < 4; ++cf) {
          int r = wc * 64 + cf * 16 + l15;
          bF[pn][cf] = *(const bfrag*)&Bs[sln][r][(l4 ^ ((r >> 1) & 3)) << 3];
        }
        if (kcn < 4) {
          if (t + 1 < 16) {   // fill aPerm during first col-tile only
            #pragma unroll
            for (int rf = 0; rf < 4; ++rf) {
              int r = wr * 64 + rf * 16 + l15, j = kcn * 4 + l4;
              aPerm[kcn][rf] = *(const bfrag*)&As[r][(j ^ (r & 7)) << 3];
            }
          }
        } else {
          #pragma unroll
          for (int rf = 0; rf < 4; ++rf) {
            int r = wr * 64 + rf * 16 + l15, j = kcn * 4 + l4;
            aF[pn][rf] = *(const bfrag*)&As[r][(j ^ (r & 7)) << 3];
          }
        }
      }

      // MFMA (zero-init accumulate at kc==0)
      #pragma unroll
      for (int rf = 0; rf < 4; ++rf) {
        const bfrag a = (kc < 4) ? aPerm[kc][rf] : aF[kc & 1][rf];  // static sel
        #pragma unroll
        for (int cf = 0; cf < 4; ++cf) {
          if (kc == 0) {
            ffrag z = {0.f, 0.f, 0.f, 0.f};
            acc[rf][cf] = __builtin_amdgcn_mfma_f32_16x16x32_bf16(a, bF[0][cf], z, 0, 0, 0);
          } else {
            acc[rf][cf] = __builtin_amdgcn_mfma_f32_16x16x32_bf16(a, bF[kc & 1][cf], acc[rf][cf], 0, 0, 0);
          }
        }
      }

      if (kc == 15) {   // per-col-tile epilogue: packed-key best-2 update
        float c2p[4];
        #pragma unroll
        for (int cf = 0; cf < 4; ++cf)
          c2p[cf] = c2s[ct & 1][wc * 64 + cf * 16 + l15] + 2048.0f;  // key > 0
        #pragma unroll
        for (int rf = 0; rf < 4; ++rf)
          #pragma unroll
          for (int rg = 0; rg < 4; ++rg) {
            unsigned kk[4];
            #pragma unroll
            for (int cf = 0; cf < 4; ++cf) {
              float d = fmaf(-2.0f, acc[rf][cf][rg], c2p[cf]);
              kk[cf] = (__float_as_uint(d) & 0xFFFFFF00u) | (unsigned)((ct << 2) | cf);
            }
            unsigned kmin = min(min(kk[0], kk[1]), min(kk[2], kk[3]));
            unsigned mx = max(b0k[rf][rg], kmin);
            b0k[rf][rg] = min(b0k[rf][rg], kmin);
            b1k[rf][rg] = min(b1k[rf][rg], mx);
          }
      }
    }  // kc
  }    // ct

  // per-row min across the 16 lanes sharing l4, cross-wave (wc) via LDS
  unsigned gmin[4][4];
  #pragma unroll
  for (int rf = 0; rf < 4; ++rf)
    #pragma unroll
    for (int rg = 0; rg < 4; ++rg) {
      unsigned g = b0k[rf][rg];
      #pragma unroll
      for (int m = 1; m < 16; m <<= 1)
        g = min(g, (unsigned)__shfl_xor((int)g, m, 64));
      gmin[rf][rg] = g;
      if (l15 == 0) dstar[wc][wr * 64 + rf * 16 + l4 * 4 + rg] = g;
    }
  __syncthreads();
  #pragma unroll
  for (int rf = 0; rf < 4; ++rf)
    #pragma unroll
    for (int rg = 0; rg < 4; ++rg) {
      int rl = wr * 64 + rf * 16 + l4 * 4 + rg;
      unsigned gg = min(gmin[rf][rg], dstar[wc ^ 1][rl]);
      float ds = __uint_as_float(gg & 0xFFFFFF00u);
      unsigned thr = __float_as_uint(ds + MARGIN);
      int base = (row0 + rl) * 64 + wc * 32 + l15 * 2;
      unsigned k0 = b0k[rf][rg], k1 = b1k[rf][rg];
      int c0 = (int)(((k0 >> 2) & 63u) * 128u) + wc * 64 + (int)(k0 & 3u) * 16 + l15;
      int c1 = (int)(((k1 >> 2) & 63u) * 128u) + wc * 64 + (int)(k1 & 3u) * 16 + l15;
      cand[base + 0] = (k0 <= thr) ? c0 : -1;
      cand[base + 1] = (k1 <= thr) ? c1 : -1;
    }
}

// ---- exact fp64 refine over candidate set (one wave per row) ---------------
__global__ void vq_refine(const float* __restrict__ X, const float* __restrict__ Cb,
                          const int* __restrict__ cand, float* __restrict__ idx_out) {
  int row = (blockIdx.x * blockDim.x + threadIdx.x) >> 6;
  int lane = threadIdx.x & 63;
  if (row >= NTOK) return;
  int cv = cand[row * 64 + lane];
  unsigned long long mask = __ballot(cv >= 0);
  if (__popcll(mask) == 1) {
    int src = __ffsll(mask) - 1;
    int idx = __shfl(cv, src, 64);
    if (lane == 0) idx_out[row] = (float)idx;
    return;
  }
  const float4* x4 = (const float4*)(X + (size_t)row * DIM);
  float4 xa = x4[lane * 2], xb = x4[lane * 2 + 1];
  double bestd = 1e300; int besti = 0;
  unsigned long long mm = mask;
  while (mm) {
    int src = __ffsll(mm) - 1; mm &= mm - 1;
    int idx = __shfl(cv, src, 64);
    const float4* c4 = (const float4*)(Cb + (size_t)idx * DIM);
    float4 ca = c4[lane * 2], cb = c4[lane * 2 + 1];
    double dt = (double)xa.x*ca.x + (double)xa.y*ca.y + (double)xa.z*ca.z + (double)xa.w*ca.w
              + (double)xb.x*cb.x + (double)xb.y*cb.y + (double)xb.z*cb.z + (double)xb.w*cb.w;
    double cc = (double)ca.x*ca.x + (double)ca.y*ca.y + (double)ca.z*ca.z + (double)ca.w*ca.w
              + (double)cb.x*cb.x + (double)cb.y*cb.y + (double)cb.z*cb.z + (double)cb.w*cb.w;
    double s = cc - 2.0 * dt;               // x2 omitted: per-row constant
    #pragma unroll
    for (int off = 32; off; off >>= 1) s += __shfl_down(s, off, 64);
    if (lane == 0 && (s < bestd || (s == bestd && idx < besti))) { bestd = s; besti = idx; }
  }
  if (lane == 0) idx_out[row] = (float)besti;
}

// ---- final: quantized = inputs (runs LAST; overwrites scratch) -------------
__global__ void vq_copy(const float* __restrict__ in, float* __restrict__ out, int n4) {
  int i = blockIdx.x * blockDim.x + threadIdx.x;
  int st = gridDim.x * blockDim.x;
  const float4* s = (const float4*)in;
  float4* d = (float4*)out;
  for (; i < n4; i += st) d[i] = s[i];
}

extern "C" void kernel_launch(void* const* d_in, const int* in_sizes, int n_in,
                              void* d_out, int out_size, void* d_ws, size_t ws_size,
                              hipStream_t stream) {
  const float* X  = (const float*)d_in[0];
  const float* Cb = (const float*)d_in[1];
  float* out = (float*)d_out;

  unsigned short* Xb  = (unsigned short*)out;                 // [N][D] bf16
  unsigned short* Cbb = (unsigned short*)(out + 8388608);     // [K][D] bf16
  int*            cand = (int*)(out + 12582912);              // [N][64]
  float*          c2   = out + 14680064;                      // [K]
  float*          idx_out = out + (size_t)NTOK * DIM;

  vq_prep<<<KCODES / 4, 256, 0, stream>>>(Cb, Cbb, c2, KCODES);
  vq_prep<<<NTOK / 4, 256, 0, stream>>>(X, Xb, nullptr, NTOK);
  vq_main<<<NTOK / BM, 256, 0, stream>>>(Xb, Cbb, c2, cand);
  vq_refine<<<NTOK / 4, 256, 0, stream>>>(X, Cb, cand, idx_out);
  vq_copy<<<2048, 256, 0, stream>>>(X, out, NTOK * DIM / 4);
}